// Round 13
// baseline (100.105 us; speedup 1.0000x reference)
//
#include <hip/hip_runtime.h>

#define POOL_H 7
#define POOL_W 7
#define BINS   49
#define SR 2
#define SCALE 0.25f
#define CH 256          // channels (fixed by problem)

typedef unsigned int   u32;
typedef unsigned short u16;
typedef unsigned long long u64;
typedef float f2v __attribute__((ext_vector_type(2)));
typedef f2v uf2 __attribute__((aligned(4)));
typedef float f4  __attribute__((ext_vector_type(4)));
typedef u32  ui4 __attribute__((ext_vector_type(4)));

__device__ __forceinline__ u16 f32_to_bf16_rne(float f) {
    u32 u = __builtin_bit_cast(u32, f);
    u32 r = (u + 0x7FFFu + ((u >> 16) & 1u)) >> 16;
    return (u16)r;
}
__device__ __forceinline__ float bf16lo(u32 u) { return __builtin_bit_cast(float, u << 16); }
__device__ __forceinline__ float bf16hi(u32 u) { return __builtin_bit_cast(float, u & 0xFFFF0000u); }

// ---------------- Pass 1: NCHW f32 -> NHWC bf16 transpose + ROI spatial sort
// Tile = 256 c x 256 hw (one block covers ALL channels of a 256-hw window):
//  - reads: one instr = one FULL 1KB sequential channel row (64 lanes x 16B)
//  - writes: block emits a fully DENSE sequential 128KB NHWC region
// LDS: STATIC 128KB (dynamic >64KB can fail launch without opt-in; m201
// precedent: 128KiB static LDS runs on gfx950). u32 = bf16 channel-pair.
//   word(c2,hw) = c2*256 + ((hw + (c2 & ~3)) & 255)
//  - write phase (b128, hw=4*lane, c2 uniform): 8 words/bank, conflict-free
//  - store phase (c2=4j+d, hw uniform): banks (hw+4j)%32 -> 4-way (~1.58x), ok
// r12 BUG FIX: store loop now emits nhw*32 chunks (hw=id>>5, j=id&31),
// covering all 256 channels per hw (was nhw*8 -> only ch 0..63 written).
__global__ __launch_bounds__(512) void nchw_to_nhwc_bf16(
    const float* __restrict__ feat, u16* __restrict__ ft,
    const float* __restrict__ rois, int* __restrict__ perm,
    int HW, int nwin, int K, int H, int W, int N)
{
    __shared__ __attribute__((aligned(16))) u32 lds32[32768];   // 128 KB static
    int t = threadIdx.x;

    if ((int)blockIdx.x == gridDim.x - 1) {
        // ---- ROI spatial sort (K <= 1024); keys aliased into lds32 ----
        u64* keys = (u64*)lds32;
        int bd = (int)blockDim.x;
        for (int v = t; v < 1024; v += bd) {
            u64 kv = ~0ull;
            if (v < K) {
                const float* rp = rois + (size_t)v * 5;
                int b = (int)rp[0];
                float cx = 0.5f * (rp[1] + rp[3]) * SCALE;
                float cy = 0.5f * (rp[2] + rp[4]) * SCALE;
                int qx = min(15, max(0, (int)(cx * (16.0f / (float)W))));
                int qy = min(15, max(0, (int)(cy * (16.0f / (float)H))));
                u32 m = 0;
                #pragma unroll
                for (int i = 0; i < 4; ++i)
                    m |= (((qy >> i) & 1u) << (2 * i + 1)) | (((qx >> i) & 1u) << (2 * i));
                u32 key = ((u32)b << 8) | m;
                kv = ((u64)key << 32) | (u32)v;
            }
            keys[v] = kv;
        }
        __syncthreads();
        for (int size = 2; size <= 1024; size <<= 1) {
            for (int stride = size >> 1; stride > 0; stride >>= 1) {
                for (int v = t; v < 1024; v += bd) {
                    int j = v ^ stride;
                    if (j > v) {
                        bool up = ((v & size) == 0);
                        u64 a = keys[v], bb = keys[j];
                        if ((a > bb) == up) { keys[v] = bb; keys[j] = a; }
                    }
                }
                __syncthreads();
            }
        }
        for (int v = t; v < K; v += bd)
            perm[v] = (int)(keys[v] & 0xffffffffu);
        return;
    }

    int bid = blockIdx.x;
    int b   = bid % N;
    int win = bid / N;
    int hw0 = win * 256;
    int nhw = min(256, HW - hw0);       // 256, or 64 tail (40000 = 156*256+64)

    int lane = t & 63;
    int w    = t >> 6;                  // wave 0..7

    const float* src = feat + (size_t)b * CH * HW + hw0 + 4 * lane;
    bool lok = (4 * lane) < nhw;        // tail guard (never read OOB)

    // ---- read + stage: wave w owns channel-pairs c2 = w*16 .. w*16+15.
    // Each pair: 2 instrs x 1KB sequential row; pack -> one b128 LDS write.
    #pragma unroll 4
    for (int p = 0; p < 16; ++p) {
        int c2 = w * 16 + p;
        int c0 = 2 * c2;
        f4 vA = {0.f,0.f,0.f,0.f}, vB = {0.f,0.f,0.f,0.f};
        if (lok) {
            vA = *(const f4*)(src + (size_t)c0 * HW);
            vB = *(const f4*)(src + (size_t)(c0 + 1) * HW);
        }
        ui4 o;
        o.x = ((u32)f32_to_bf16_rne(vB.x) << 16) | (u32)f32_to_bf16_rne(vA.x);
        o.y = ((u32)f32_to_bf16_rne(vB.y) << 16) | (u32)f32_to_bf16_rne(vA.y);
        o.z = ((u32)f32_to_bf16_rne(vB.z) << 16) | (u32)f32_to_bf16_rne(vA.z);
        o.w = ((u32)f32_to_bf16_rne(vB.w) << 16) | (u32)f32_to_bf16_rne(vA.w);
        int rot  = c2 & ~3;             // 4*(c2>>2): keeps b128 4-aligned
        int word = c2 * 256 + ((4 * lane + rot) & 255);
        *(ui4*)&lds32[word] = o;
    }
    __syncthreads();

    // ---- store: dense region. 16B chunk = 4 c2-words = 8 channels.
    // chunks = nhw * 32;  id -> hw = id>>5, j = id&31; c2 = 4j+d.
    u16* dst = ft + ((size_t)b * HW + hw0) * CH;
    int niter = nhw >> 4;               // 16 (full) or 4 (tail)
    for (int i = 0; i < niter; ++i) {
        int id = i * 512 + t;           // [0, nhw*32)
        int hw = id >> 5;
        int j  = id & 31;
        u32 o[4];
        #pragma unroll
        for (int d = 0; d < 4; ++d) {
            int c2 = 4 * j + d;
            o[d] = lds32[c2 * 256 + ((hw + 4 * j) & 255)];
        }
        *(ui4*)(dst + (size_t)hw * CH + 8 * j) = *(ui4*)o;
    }
}

// ---------------- Pass 2: gather from NHWC bf16 (row-split waves) -----------
__global__ __launch_bounds__(448) void roi_gather_nhwc(
    const u16* __restrict__ ft,      // [N][H][W][CH] bf16
    const float* __restrict__ rois,  // [K][5]
    const int* __restrict__ perm,    // [K] spatial order
    float* __restrict__ out,         // [K][CH][7][7]
    int H, int W, int K, int chunk, int do_swz)
{
    int bid  = blockIdx.x;
    int slot = do_swz ? (bid & 7) * chunk + (bid >> 3) : bid;
    int k    = perm[slot / 7];
    int q    = slot % 7;             // pooled row ph == q
    int bin0 = q * 7;

    __shared__ float lds[7][CH];     // 7 KB

    int lane = threadIdx.x & 63;
    int w    = threadIdx.x >> 6;     // wave = pw (bin col), 0..6
    int half = lane >> 5;            // 0: y0 row, 1: y1 row
    int lc   = lane & 31;            // channel group: ch 8*lc .. 8*lc+7

    const float* rp = rois + (size_t)k * 5;
    int   b   = (int)rp[0];
    float rx1 = rp[1] * SCALE - 0.5f;
    float ry1 = rp[2] * SCALE - 0.5f;
    float rx2 = rp[3] * SCALE - 0.5f;
    float ry2 = rp[4] * SCALE - 0.5f;
    float bin_h = (ry2 - ry1) * (1.0f / POOL_H);
    float bin_w = (rx2 - rx1) * (1.0f / POOL_W);

    const u16* fbase = ft + (size_t)b * H * W * CH + lc * 8;

    int ph = q;
    int pw = w;

    float acc[8];
    #pragma unroll
    for (int j = 0; j < 8; ++j) acc[j] = 0.0f;

    #pragma unroll
    for (int iy = 0; iy < SR; ++iy) {
        float y = ry1 + ((float)ph + ((float)iy + 0.5f) * (1.0f / SR)) * bin_h;
        bool vy = (y > -1.0f) && (y < (float)H);
        float yc = fminf(fmaxf(y, 0.0f), (float)(H - 1));
        int   y0 = (int)yc;
        int   y1 = min(y0 + 1, H - 1);
        float ly = yc - (float)y0;
        float hy = 1.0f - ly;
        int   ysel = half ? y1 : y0;       // per-lane row select
        float wrow = half ? ly : hy;       // per-lane row weight
        #pragma unroll
        for (int ix = 0; ix < SR; ++ix) {
            float x = rx1 + ((float)pw + ((float)ix + 0.5f) * (1.0f / SR)) * bin_w;
            bool vx = (x > -1.0f) && (x < (float)W);
            if (!(vy && vx)) continue;     // wave-uniform branch
            float xc = fminf(fmaxf(x, 0.0f), (float)(W - 1));
            int   x0 = (int)xc;
            int   x1 = min(x0 + 1, W - 1);
            float lx = xc - (float)x0;

            const u16* p0 = fbase + (size_t)(ysel * W + x0) * CH;
            ui4 A = *(const ui4*)p0;                               // (row, x0) 8ch
            ui4 B = *(const ui4*)(p0 + (size_t)(x1 - x0) * CH);    // (row, x1) 8ch

            #pragma unroll
            for (int j = 0; j < 4; ++j) {
                float a0 = bf16lo(A[j]), a1 = bf16hi(A[j]);
                float b0 = bf16lo(B[j]), b1 = bf16hi(B[j]);
                float r0 = a0 + lx * (b0 - a0);
                float r1 = a1 + lx * (b1 - a1);
                acc[2 * j]     += wrow * r0;
                acc[2 * j + 1] += wrow * r1;
            }
        }
    }

    #pragma unroll
    for (int j = 0; j < 8; ++j)
        acc[j] = (acc[j] + __shfl_xor(acc[j], 32, 64)) * 0.25f;

    if (half == 0) {
        f4 lo = { acc[0], acc[1], acc[2], acc[3] };
        f4 hi = { acc[4], acc[5], acc[6], acc[7] };
        *(f4*)&lds[w][lc * 8]     = lo;
        *(f4*)&lds[w][lc * 8 + 4] = hi;
    }
    __syncthreads();

    float* ob = out + (size_t)k * CH * BINS + bin0;
    for (int id = (int)threadIdx.x; id < 7 * CH; id += 448) {
        int c  = id / 7;
        int lb = id % 7;
        ob[(size_t)c * BINS + lb] = lds[lb][c];
    }
}

// ---------------- Fallback (round-3 kernel) if ws too small -----------------
#define NC 2
#define NXCD 8
__global__ __launch_bounds__(256) void roi_align_fallback(
    const float* __restrict__ feat, const float* __restrict__ rois,
    float* __restrict__ out, int C, int H, int W, int K,
    int blocks_per_slice, int slices_per_xcd)
{
    int wgid  = blockIdx.x;
    int g     = wgid % NXCD;
    int r     = wgid / NXCD;
    int slice = g * slices_per_xcd + r / blocks_per_slice;
    int j     = r % blocks_per_slice;
    int tid = j * (int)blockDim.x + (int)threadIdx.x;
    int k   = tid / BINS;
    int bin = tid % BINS;
    if (k >= K) return;
    int pw = bin % POOL_W, ph = bin / POOL_W, c2 = slice;

    const float* rp = rois + (size_t)k * 5;
    int b = (int)rp[0];
    float rx1 = rp[1]*SCALE-0.5f, ry1 = rp[2]*SCALE-0.5f;
    float rx2 = rp[3]*SCALE-0.5f, ry2 = rp[4]*SCALE-0.5f;
    float bin_h = (ry2-ry1)*(1.0f/POOL_H), bin_w = (rx2-rx1)*(1.0f/POOL_W);

    int yr0[SR], yr1[SR]; float ly[SR], hy[SR]; bool vy[SR];
    #pragma unroll
    for (int iy = 0; iy < SR; ++iy) {
        float y = ry1 + ((float)ph + ((float)iy+0.5f)*(1.0f/SR))*bin_h;
        vy[iy] = (y > -1.0f) && (y < (float)H);
        float yc = fminf(fmaxf(y, 0.0f), (float)(H-1));
        int y0 = (int)yc; yr0[iy]=y0; yr1[iy]=min(y0+1,H-1);
        ly[iy]=yc-(float)y0; hy[iy]=1.0f-ly[iy];
    }
    int xl[SR]; float lx[SR]; bool vx[SR], xhi[SR];
    #pragma unroll
    for (int ix = 0; ix < SR; ++ix) {
        float x = rx1 + ((float)pw + ((float)ix+0.5f)*(1.0f/SR))*bin_w;
        vx[ix] = (x > -1.0f) && (x < (float)W);
        float xc = fminf(fmaxf(x, 0.0f), (float)(W-1));
        int x0 = (int)xc; int xload = min(x0, W-2);
        xl[ix]=xload; xhi[ix]=(x0>xload); lx[ix]=xc-(float)x0;
    }
    const size_t HW = (size_t)H*W;
    const float* fmap = feat + ((size_t)b*C + (size_t)c2*NC)*HW;
    float acc[NC];
    #pragma unroll
    for (int cc=0; cc<NC; ++cc) acc[cc]=0.0f;
    #pragma unroll
    for (int iy=0; iy<SR; ++iy)
      #pragma unroll
      for (int ix=0; ix<SR; ++ix)
        if (vy[iy] && vx[ix]) {
            int off0 = yr0[iy]*W + xl[ix], off1 = yr1[iy]*W + xl[ix];
            #pragma unroll
            for (int cc=0; cc<NC; ++cc) {
                const float* base = fmap + (size_t)cc*HW;
                f2v d0 = *(const uf2*)(base + off0);
                f2v d1 = *(const uf2*)(base + off1);
                float v00 = xhi[ix] ? d0.y : d0.x;
                float v10 = xhi[ix] ? d1.y : d1.x;
                float r0 = v00 + lx[ix]*(d0.y - v00);
                float r1 = v10 + lx[ix]*(d1.y - v10);
                acc[cc] += hy[iy]*r0 + ly[iy]*r1;
            }
        }
    size_t obase = ((size_t)k*C + (size_t)c2*NC)*BINS + bin;
    #pragma unroll
    for (int cc=0; cc<NC; ++cc)
        out[obase + (size_t)cc*BINS] = acc[cc]*(1.0f/(SR*SR));
}

extern "C" void kernel_launch(void* const* d_in, const int* in_sizes, int n_in,
                              void* d_out, int out_size, void* d_ws, size_t ws_size,
                              hipStream_t stream) {
    const float* feat = (const float*)d_in[0];
    const float* rois = (const float*)d_in[1];
    float* out = (float*)d_out;

    const int C = 256, H = 200, W = 200;
    const int HW = H * W;
    const int K = in_sizes[1] / 5;
    const int N = in_sizes[0] / (C * HW);

    size_t nhwc_bytes = (size_t)N * HW * CH * sizeof(u16);   // 82 MB for N=4
    size_t need = nhwc_bytes + (size_t)K * sizeof(int);
    if (ws_size >= need && K <= 1024 && (HW % 64) == 0) {
        u16* ft   = (u16*)d_ws;
        int* perm = (int*)((char*)d_ws + nhwc_bytes);
        const int nwin = (HW + 255) / 256;                   // 157
        nchw_to_nhwc_bf16<<<nwin * N + 1, 512, 0, stream>>>(
            feat, ft, rois, perm, HW, nwin, K, H, W, N);
        int grid  = K * 7;                                   // 7168 for K=1024
        int swz   = (grid % 8) == 0;
        int chunk = grid / 8;
        roi_gather_nhwc<<<grid, 448, 0, stream>>>(
            (const u16*)ft, rois, perm, out, H, W, K, chunk, swz);
    } else {
        const int threads_per_slice = K * BINS;
        const int block = 256;
        const int blocks_per_slice = (threads_per_slice + block - 1) / block;
        const int slices = C / NC;
        const int slices_per_xcd = slices / NXCD;
        const int grid = slices * blocks_per_slice;
        roi_align_fallback<<<grid, block, 0, stream>>>(feat, rois, out, C, H, W, K,
                                                       blocks_per_slice, slices_per_xcd);
    }
}

// Round 14
// 92.567 us; speedup vs baseline: 1.0814x; 1.0814x over previous
//
#include <hip/hip_runtime.h>

#define POOL_H 7
#define POOL_W 7
#define BINS   49
#define SR 2
#define SCALE 0.25f
#define CH 256          // channels (fixed by problem)

typedef unsigned int   u32;
typedef unsigned short u16;
typedef unsigned long long u64;
typedef float f2v __attribute__((ext_vector_type(2)));
typedef f2v uf2 __attribute__((aligned(4)));
typedef float f4  __attribute__((ext_vector_type(4)));
typedef u16  us4 __attribute__((ext_vector_type(4)));
typedef u32  ui2 __attribute__((ext_vector_type(2)));
typedef u32  ui4 __attribute__((ext_vector_type(4)));

__device__ __forceinline__ u16 f32_to_bf16_rne(float f) {
    u32 u = __builtin_bit_cast(u32, f);
    u32 r = (u + 0x7FFFu + ((u >> 16) & 1u)) >> 16;
    return (u16)r;
}
__device__ __forceinline__ float bf16lo(u32 u) { return __builtin_bit_cast(float, u << 16); }
__device__ __forceinline__ float bf16hi(u32 u) { return __builtin_bit_cast(float, u & 0xFFFF0000u); }

// ---------------- Pass 1: NCHW f32 -> NHWC bf16 transpose + ROI spatial sort
// (Best-measured config, round 8: ~77us.) 512 threads, 33KB LDS.
// Read loop compile-time bounded + unrolled (512B dwordx2 bursts);
// stores one dwordx4 per thread-iter (dense 1KB/wave).
__global__ __launch_bounds__(512) void nchw_to_nhwc_bf16(
    const float* __restrict__ feat, u16* __restrict__ ft,
    const float* __restrict__ rois, int* __restrict__ perm,
    int HW, int tiles, int K, int H, int W)
{
    extern __shared__ __align__(16) unsigned char smem[];   // 64 KB dynamic

    int t = threadIdx.x;

    if ((int)blockIdx.x == gridDim.x - 1) {
        // ---- ROI spatial sort (K <= 1024) ----
        u64* keys = (u64*)smem;
        int bd = (int)blockDim.x;
        for (int v = t; v < 1024; v += bd) {
            u64 kv = ~0ull;
            if (v < K) {
                const float* rp = rois + (size_t)v * 5;
                int b = (int)rp[0];
                float cx = 0.5f * (rp[1] + rp[3]) * SCALE;
                float cy = 0.5f * (rp[2] + rp[4]) * SCALE;
                int qx = min(15, max(0, (int)(cx * (16.0f / (float)W))));
                int qy = min(15, max(0, (int)(cy * (16.0f / (float)H))));
                u32 m = 0;
                #pragma unroll
                for (int i = 0; i < 4; ++i)
                    m |= (((qy >> i) & 1u) << (2 * i + 1)) | (((qx >> i) & 1u) << (2 * i));
                u32 key = ((u32)b << 8) | m;
                kv = ((u64)key << 32) | (u32)v;
            }
            keys[v] = kv;
        }
        __syncthreads();
        for (int size = 2; size <= 1024; size <<= 1) {
            for (int stride = size >> 1; stride > 0; stride >>= 1) {
                for (int v = t; v < 1024; v += bd) {
                    int j = v ^ stride;
                    if (j > v) {
                        bool up = ((v & size) == 0);
                        u64 a = keys[v], bb = keys[j];
                        if ((a > bb) == up) { keys[v] = bb; keys[j] = a; }
                    }
                }
                __syncthreads();
            }
        }
        for (int v = t; v < K; v += bd)
            perm[v] = (int)(keys[v] & 0xffffffffu);
        return;
    }

    u32* lds32 = (u32*)smem;            // logical [256][64] u32, swizzled
    int b    = blockIdx.x / tiles;
    int tile = blockIdx.x % tiles;
    int hw0  = tile * 128;
    int nhw  = min(128, HW - hw0);      // 128 or 64 (40000 = 312*128 + 64)

    int lane = t & 63;
    int w    = t >> 6;                  // 0..7

    const float* src = feat + (size_t)b * CH * HW + hw0;
    if (nhw == 128) {
        #pragma unroll 8
        for (int ci = 0; ci < 32; ++ci) {
            int c = w * 32 + ci;
            f2v v = *(const f2v*)(src + (size_t)c * HW + 2 * lane);
            u32 p = ((u32)f32_to_bf16_rne(v.y) << 16) | (u32)f32_to_bf16_rne(v.x);
            lds32[c * 64 + ((lane + (c >> 3)) & 63)] = p;
        }
    } else {
        #pragma unroll 8
        for (int ci = 0; ci < 32; ++ci) {
            int c = w * 32 + ci;
            float v = src[(size_t)c * HW + lane];
            u16 h = f32_to_bf16_rne(v);
            u16* ph = (u16*)&lds32[c * 64 + (((lane >> 1) + (c >> 3)) & 63)];
            ph[lane & 1] = h;
        }
    }
    __syncthreads();

    // Store: 16B NHWC chunk per thread-iter; wave writes 1KB contiguous.
    u16* dst = ft + ((size_t)b * HW + hw0) * CH;
    int cg     = t & 31;                // channel group: c = 8*cg .. 8*cg+7
    int hw_off = t >> 5;                // [0,16)
    int iters  = nhw >> 4;              // 8 or 4
    for (int i = 0; i < iters; ++i) {
        int hw  = i * 16 + hw_off;
        int m   = hw >> 1;
        int sel = hw & 1;
        u32 vals[8];
        #pragma unroll
        for (int j = 0; j < 8; ++j) {
            int c = 8 * cg + j;
            vals[j] = lds32[c * 64 + ((m + cg) & 63)];
        }
        ui4 o;
        #pragma unroll
        for (int d = 0; d < 4; ++d) {
            u32 lo16 = sel ? (vals[2 * d]     >> 16) : (vals[2 * d]     & 0xFFFFu);
            u32 hi16 = sel ? (vals[2 * d + 1] >> 16) : (vals[2 * d + 1] & 0xFFFFu);
            o[d] = (hi16 << 16) | lo16;
        }
        *(ui4*)(dst + (size_t)hw * CH + cg * 8) = o;
    }
}

// ---------------- Pass 2: gather from NHWC bf16 (row-split waves) -----------
__global__ __launch_bounds__(448) void roi_gather_nhwc(
    const u16* __restrict__ ft,      // [N][H][W][CH] bf16
    const float* __restrict__ rois,  // [K][5]
    const int* __restrict__ perm,    // [K] spatial order
    float* __restrict__ out,         // [K][CH][7][7]
    int H, int W, int K, int chunk, int do_swz)
{
    int bid  = blockIdx.x;
    int slot = do_swz ? (bid & 7) * chunk + (bid >> 3) : bid;
    int k    = perm[slot / 7];
    int q    = slot % 7;             // pooled row ph == q
    int bin0 = q * 7;

    __shared__ float lds[7][CH];     // 7 KB

    int lane = threadIdx.x & 63;
    int w    = threadIdx.x >> 6;     // wave = pw (bin col), 0..6
    int half = lane >> 5;            // 0: y0 row, 1: y1 row
    int lc   = lane & 31;            // channel group: ch 8*lc .. 8*lc+7

    const float* rp = rois + (size_t)k * 5;
    int   b   = (int)rp[0];
    float rx1 = rp[1] * SCALE - 0.5f;
    float ry1 = rp[2] * SCALE - 0.5f;
    float rx2 = rp[3] * SCALE - 0.5f;
    float ry2 = rp[4] * SCALE - 0.5f;
    float bin_h = (ry2 - ry1) * (1.0f / POOL_H);
    float bin_w = (rx2 - rx1) * (1.0f / POOL_W);

    const u16* fbase = ft + (size_t)b * H * W * CH + lc * 8;

    int ph = q;
    int pw = w;

    float acc[8];
    #pragma unroll
    for (int j = 0; j < 8; ++j) acc[j] = 0.0f;

    #pragma unroll
    for (int iy = 0; iy < SR; ++iy) {
        float y = ry1 + ((float)ph + ((float)iy + 0.5f) * (1.0f / SR)) * bin_h;
        bool vy = (y > -1.0f) && (y < (float)H);
        float yc = fminf(fmaxf(y, 0.0f), (float)(H - 1));
        int   y0 = (int)yc;
        int   y1 = min(y0 + 1, H - 1);
        float ly = yc - (float)y0;
        float hy = 1.0f - ly;
        int   ysel = half ? y1 : y0;       // per-lane row select
        float wrow = half ? ly : hy;       // per-lane row weight
        #pragma unroll
        for (int ix = 0; ix < SR; ++ix) {
            float x = rx1 + ((float)pw + ((float)ix + 0.5f) * (1.0f / SR)) * bin_w;
            bool vx = (x > -1.0f) && (x < (float)W);
            if (!(vy && vx)) continue;     // wave-uniform branch
            float xc = fminf(fmaxf(x, 0.0f), (float)(W - 1));
            int   x0 = (int)xc;
            int   x1 = min(x0 + 1, W - 1);
            float lx = xc - (float)x0;

            const u16* p0 = fbase + (size_t)(ysel * W + x0) * CH;
            ui4 A = *(const ui4*)p0;                               // (row, x0) 8ch
            ui4 B = *(const ui4*)(p0 + (size_t)(x1 - x0) * CH);    // (row, x1) 8ch

            #pragma unroll
            for (int j = 0; j < 4; ++j) {
                float a0 = bf16lo(A[j]), a1 = bf16hi(A[j]);
                float b0 = bf16lo(B[j]), b1 = bf16hi(B[j]);
                float r0 = a0 + lx * (b0 - a0);
                float r1 = a1 + lx * (b1 - a1);
                acc[2 * j]     += wrow * r0;
                acc[2 * j + 1] += wrow * r1;
            }
        }
    }

    #pragma unroll
    for (int j = 0; j < 8; ++j)
        acc[j] = (acc[j] + __shfl_xor(acc[j], 32, 64)) * 0.25f;

    if (half == 0) {
        f4 lo = { acc[0], acc[1], acc[2], acc[3] };
        f4 hi = { acc[4], acc[5], acc[6], acc[7] };
        *(f4*)&lds[w][lc * 8]     = lo;
        *(f4*)&lds[w][lc * 8 + 4] = hi;
    }
    __syncthreads();

    float* ob = out + (size_t)k * CH * BINS + bin0;
    for (int id = (int)threadIdx.x; id < 7 * CH; id += 448) {
        int c  = id / 7;
        int lb = id % 7;
        ob[(size_t)c * BINS + lb] = lds[lb][c];
    }
}

// ---------------- Fallback (round-3 kernel) if ws too small -----------------
#define NC 2
#define NXCD 8
__global__ __launch_bounds__(256) void roi_align_fallback(
    const float* __restrict__ feat, const float* __restrict__ rois,
    float* __restrict__ out, int C, int H, int W, int K,
    int blocks_per_slice, int slices_per_xcd)
{
    int wgid  = blockIdx.x;
    int g     = wgid % NXCD;
    int r     = wgid / NXCD;
    int slice = g * slices_per_xcd + r / blocks_per_slice;
    int j     = r % blocks_per_slice;
    int tid = j * (int)blockDim.x + (int)threadIdx.x;
    int k   = tid / BINS;
    int bin = tid % BINS;
    if (k >= K) return;
    int pw = bin % POOL_W, ph = bin / POOL_W, c2 = slice;

    const float* rp = rois + (size_t)k * 5;
    int b = (int)rp[0];
    float rx1 = rp[1]*SCALE-0.5f, ry1 = rp[2]*SCALE-0.5f;
    float rx2 = rp[3]*SCALE-0.5f, ry2 = rp[4]*SCALE-0.5f;
    float bin_h = (ry2-ry1)*(1.0f/POOL_H), bin_w = (rx2-rx1)*(1.0f/POOL_W);

    int yr0[SR], yr1[SR]; float ly[SR], hy[SR]; bool vy[SR];
    #pragma unroll
    for (int iy = 0; iy < SR; ++iy) {
        float y = ry1 + ((float)ph + ((float)iy+0.5f)*(1.0f/SR))*bin_h;
        vy[iy] = (y > -1.0f) && (y < (float)H);
        float yc = fminf(fmaxf(y, 0.0f), (float)(H-1));
        int y0 = (int)yc; yr0[iy]=y0; yr1[iy]=min(y0+1,H-1);
        ly[iy]=yc-(float)y0; hy[iy]=1.0f-ly[iy];
    }
    int xl[SR]; float lx[SR]; bool vx[SR], xhi[SR];
    #pragma unroll
    for (int ix = 0; ix < SR; ++ix) {
        float x = rx1 + ((float)pw + ((float)ix+0.5f)*(1.0f/SR))*bin_w;
        vx[ix] = (x > -1.0f) && (x < (float)W);
        float xc = fminf(fmaxf(x, 0.0f), (float)(W-1));
        int x0 = (int)xc; int xload = min(x0, W-2);
        xl[ix]=xload; xhi[ix]=(x0>xload); lx[ix]=xc-(float)x0;
    }
    const size_t HW = (size_t)H*W;
    const float* fmap = feat + ((size_t)b*C + (size_t)c2*NC)*HW;
    float acc[NC];
    #pragma unroll
    for (int cc=0; cc<NC; ++cc) acc[cc]=0.0f;
    #pragma unroll
    for (int iy=0; iy<SR; ++iy)
      #pragma unroll
      for (int ix=0; ix<SR; ++ix)
        if (vy[iy] && vx[ix]) {
            int off0 = yr0[iy]*W + xl[ix], off1 = yr1[iy]*W + xl[ix];
            #pragma unroll
            for (int cc=0; cc<NC; ++cc) {
                const float* base = fmap + (size_t)cc*HW;
                f2v d0 = *(const uf2*)(base + off0);
                f2v d1 = *(const uf2*)(base + off1);
                float v00 = xhi[ix] ? d0.y : d0.x;
                float v10 = xhi[ix] ? d1.y : d1.x;
                float r0 = v00 + lx[ix]*(d0.y - v00);
                float r1 = v10 + lx[ix]*(d1.y - v10);
                acc[cc] += hy[iy]*r0 + ly[iy]*r1;
            }
        }
    size_t obase = ((size_t)k*C + (size_t)c2*NC)*BINS + bin;
    #pragma unroll
    for (int cc=0; cc<NC; ++cc)
        out[obase + (size_t)cc*BINS] = acc[cc]*(1.0f/(SR*SR));
}

extern "C" void kernel_launch(void* const* d_in, const int* in_sizes, int n_in,
                              void* d_out, int out_size, void* d_ws, size_t ws_size,
                              hipStream_t stream) {
    const float* feat = (const float*)d_in[0];
    const float* rois = (const float*)d_in[1];
    float* out = (float*)d_out;

    const int C = 256, H = 200, W = 200;
    const int HW = H * W;
    const int K = in_sizes[1] / 5;
    const int N = in_sizes[0] / (C * HW);

    size_t nhwc_bytes = (size_t)N * HW * CH * sizeof(u16);   // 82 MB for N=4
    size_t need = nhwc_bytes + (size_t)K * sizeof(int);
    if (ws_size >= need && (HW % 64) == 0 && K <= 1024) {
        u16* ft   = (u16*)d_ws;
        int* perm = (int*)((char*)d_ws + nhwc_bytes);
        const int tiles = (HW + 127) / 128;                  // 313
        nchw_to_nhwc_bf16<<<N * tiles + 1, 512, 65536, stream>>>(
            feat, ft, rois, perm, HW, tiles, K, H, W);
        int grid  = K * 7;                                   // 7168 for K=1024
        int swz   = (grid % 8) == 0;
        int chunk = grid / 8;
        roi_gather_nhwc<<<grid, 448, 0, stream>>>(
            (const u16*)ft, rois, perm, out, H, W, K, chunk, swz);
    } else {
        const int threads_per_slice = K * BINS;
        const int block = 256;
        const int blocks_per_slice = (threads_per_slice + block - 1) / block;
        const int slices = C / NC;
        const int slices_per_xcd = slices / NXCD;
        const int grid = slices * blocks_per_slice;
        roi_align_fallback<<<grid, block, 0, stream>>>(feat, rois, out, C, H, W, K,
                                                       blocks_per_slice, slices_per_xcd);
    }
}